// Round 13
// baseline (128.130 us; speedup 1.0000x reference)
//
#include <hip/hip_runtime.h>
#include <hip/hip_bf16.h>
#include <stdint.h>

constexpr int NN = 1024;   // nodes
constexpr int DD = 128;    // NODE_DIM == HID
constexpr int EDIM = 32;   // EDGE_DIM
constexpr int NR = 16;     // NREL

using short4v = __attribute__((ext_vector_type(4))) short;
using short8v = __attribute__((ext_vector_type(8))) short;
using f32x4   = __attribute__((ext_vector_type(4))) float;

__device__ __forceinline__ short f2bf(float x) {
  __hip_bfloat16 h = __float2bfloat16(x);   // RNE
  return __builtin_bit_cast(short, h);
}

__device__ __forceinline__ void nt_store4(float* p, const float4& v) {
  f32x4 t;
  t[0] = v.x; t[1] = v.y; t[2] = v.z; t[3] = v.w;
  __builtin_nontemporal_store(t, (f32x4*)p);
}

// ---------------- K2a v2: partial[kc][i][h] (float4-over-h, b32 adj broadcast) ----
__global__ __launch_bounds__(256) void k_adjgemm(const float* __restrict__ adj,
                                                 const float* __restrict__ X,
                                                 float* __restrict__ part) {
  __shared__ float sadj[16][136];          // pad 136: conflict-free broadcast reads
  int t = threadIdx.x;
  int ic = blockIdx.x & 63, kc = blockIdx.x >> 6;
  int i0 = ic * 16, k0 = kc * 128;
  {
    int il = t >> 4;
    int kl = (t & 15) * 8;
    const float4* src = (const float4*)(adj + (size_t)(i0 + il) * NN + k0 + kl);
    *(float4*)&sadj[il][kl]     = src[0];
    *(float4*)&sadj[il][kl + 4] = src[1];
  }
  __syncthreads();
  int hq = (t & 31) * 4;                   // h quad
  int ir = t >> 5;                         // 0..7
  float4 acc0 = {0,0,0,0}, acc1 = {0,0,0,0};
  const float* Xb = X + (size_t)k0 * DD + hq;
  #pragma unroll 4
  for (int k = 0; k < 128; ++k) {
    float4 xv = *(const float4*)(Xb + (size_t)k * DD);
    float a0 = sadj[ir][k];
    float a1 = sadj[ir + 8][k];
    acc0.x += a0 * xv.x; acc0.y += a0 * xv.y; acc0.z += a0 * xv.z; acc0.w += a0 * xv.w;
    acc1.x += a1 * xv.x; acc1.y += a1 * xv.y; acc1.z += a1 * xv.z; acc1.w += a1 * xv.w;
  }
  *(float4*)(part + ((size_t)kc * NN + (i0 + ir)) * DD + hq)     = acc0;
  *(float4*)(part + ((size_t)kc * NN + (i0 + ir + 8)) * DD + hq) = acc1;
}

// ---------------- K_dense1: rowsum + aggfin + dense layer1 ----------------
__global__ __launch_bounds__(256) void k_dense1(const float* __restrict__ X,
                                                const float* __restrict__ part,
                                                const float* __restrict__ adj,
                                                const float* __restrict__ W,
                                                const float* __restrict__ b,
                                                float* __restrict__ out,
                                                float* __restrict__ rsinv) {
  __shared__ float sagg[2][128];
  __shared__ float red[4];
  int t = threadIdx.x;
  int ig = t >> 7, h = t & 127;
  int i = blockIdx.x * 2 + ig;
  {   // rowsum(adj[i]) : 128 threads x 8 floats (adj is L2-hot from k_adjgemm)
    const float4* ar = (const float4*)(adj + (size_t)i * NN);
    float4 v0 = ar[h * 2], v1 = ar[h * 2 + 1];
    float s = v0.x + v0.y + v0.z + v0.w + v1.x + v1.y + v1.z + v1.w;
    #pragma unroll
    for (int off = 32; off > 0; off >>= 1) s += __shfl_down(s, off, 64);
    if ((t & 63) == 0) red[t >> 6] = s;
  }
  __syncthreads();
  float rs = 1.0f / (red[ig * 2] + red[ig * 2 + 1] + 1e-6f);
  if (h == 0) rsinv[i] = rs;
  {
    float ss = 0.f;
    #pragma unroll
    for (int kc = 0; kc < 8; ++kc) ss += part[(size_t)kc * NN * DD + (size_t)i * DD + h];
    sagg[ig][h] = ss * rs;
  }
  __syncthreads();
  const float4* xr = (const float4*)(X + (size_t)i * DD);
  const float4* ar = (const float4*)(&sagg[ig][0]);
  const float4* w1 = (const float4*)(W + (size_t)h * 256);
  const float4* w2 = (const float4*)(W + (size_t)h * 256 + DD);
  float acc = b[h];
  #pragma unroll 8
  for (int k = 0; k < 32; ++k) {
    float4 x = xr[k], w = w1[k];
    acc += x.x * w.x + x.y * w.y + x.z * w.z + x.w * w.w;
  }
  #pragma unroll 8
  for (int k = 0; k < 32; ++k) {
    float4 y = ar[k], w = w2[k];
    acc += y.x * w.x + y.y * w.y + y.z * w.z + y.w * w.w;
  }
  out[(size_t)i * DD + h] = fmaxf(acc, 0.f);
}

// ---------------- K_dense2ab: aggfin + dense layer2 + Aib/Bmat, fused ----------------
__global__ __launch_bounds__(256) void k_dense2ab(const float* __restrict__ X,
                                                  const float* __restrict__ part,
                                                  const float* __restrict__ rsinv,
                                                  const float* __restrict__ W,
                                                  const float* __restrict__ b,
                                                  const float* __restrict__ Wc1,
                                                  const float* __restrict__ bc1,
                                                  float* __restrict__ Aib,
                                                  float* __restrict__ Bmat) {
  __shared__ float sagg[2][128];
  __shared__ float sh2[2][128];
  int t = threadIdx.x;
  int ig = t >> 7, h = t & 127;
  int i = blockIdx.x * 2 + ig;
  {
    float ss = 0.f;
    #pragma unroll
    for (int kc = 0; kc < 8; ++kc) ss += part[(size_t)kc * NN * DD + (size_t)i * DD + h];
    sagg[ig][h] = ss * rsinv[i];
  }
  __syncthreads();
  {
    const float4* xr = (const float4*)(X + (size_t)i * DD);
    const float4* ar = (const float4*)(&sagg[ig][0]);
    const float4* w1 = (const float4*)(W + (size_t)h * 256);
    const float4* w2 = (const float4*)(W + (size_t)h * 256 + DD);
    float acc = b[h];
    #pragma unroll 8
    for (int k = 0; k < 32; ++k) {
      float4 x = xr[k], w = w1[k];
      acc += x.x * w.x + x.y * w.y + x.z * w.z + x.w * w.w;
    }
    #pragma unroll 8
    for (int k = 0; k < 32; ++k) {
      float4 y = ar[k], w = w2[k];
      acc += y.x * w.x + y.y * w.y + y.z * w.z + y.w * w.w;
    }
    sh2[ig][h] = fmaxf(acc, 0.f);
  }
  __syncthreads();
  // Aib/Bmat from the in-LDS h2 row
  const float4* xr = (const float4*)(&sh2[ig][0]);
  const float4* wa = (const float4*)(Wc1 + (size_t)h * 288);
  const float4* wb = (const float4*)(Wc1 + (size_t)h * 288 + 128);
  float aa = bc1[h], bb = 0.f;
  #pragma unroll 8
  for (int k = 0; k < 32; ++k) {
    float4 x = xr[k];
    float4 a = wa[k], b2 = wb[k];
    aa += x.x * a.x + x.y * a.y + x.z * a.z + x.w * a.w;
    bb += x.x * b2.x + x.y * b2.y + x.z * b2.z + x.w * b2.w;
  }
  Aib[(size_t)i * DD + h] = aa;
  Bmat[(size_t)i * DD + h] = bb;
}

// ---------------- K7: fused edge stage (v12 = v11 with __launch_bounds__(256,1)) --
// The min-waves=1 floor raises the allocator's VGPR budget to 512: weF/wcF/bjv
// and the 6-deep edge rotation become genuinely VGPR-resident (no per-body
// v_accvgpr shuffling -> VALU/body ~halves), and occupancy self-limits to
// ~2 waves/SIMD, dropping the LDS pipe from ~118% to ~65% subscription.

#define EDGE_BODY(T, S, PF) do {                                              \
    float4 a_ = eA##S, b_ = eB##S;                                            \
    if (PF) {                                                                 \
      const float* p_ = ebl + (size_t)((T) + 6) * ((size_t)NN * EDIM);        \
      eA##S = *(const float4*)p_;                                             \
      eB##S = *(const float4*)(p_ + 4);                                       \
    }                                                                         \
    short8v ef_;                                                              \
    ef_[0]=f2bf(a_.x); ef_[1]=f2bf(a_.y); ef_[2]=f2bf(a_.z); ef_[3]=f2bf(a_.w); \
    ef_[4]=f2bf(b_.x); ef_[5]=f2bf(b_.y); ef_[6]=f2bf(b_.z); ef_[7]=f2bf(b_.w); \
    char* pw_ = psm + (((T) & 1) << 12);                                      \
    const float* ap_ = aibs + (T) * 128 + 4 * g;                              \
    _Pragma("unroll")                                                         \
    for (int n = 0; n < 8; ++n) {                                             \
      float4 av_ = *(const float4*)(ap_ + 16 * n);                            \
      f32x4 ci_;                                                              \
      ci_[0] = av_.x + bjv[n].x; ci_[1] = av_.y + bjv[n].y;                   \
      ci_[2] = av_.z + bjv[n].z; ci_[3] = av_.w + bjv[n].w;                   \
      f32x4 acc_ = __builtin_amdgcn_mfma_f32_16x16x32_bf16(weF[n], ef_, ci_, 0, 0, 0); \
      short4v pk_;                                                            \
      pk_[0] = f2bf(fmaxf(acc_[0], 0.f)); pk_[1] = f2bf(fmaxf(acc_[1], 0.f)); \
      pk_[2] = f2bf(fmaxf(acc_[2], 0.f)); pk_[3] = f2bf(fmaxf(acc_[3], 0.f)); \
      *(short4v*)(pw_ + (((n >> 1) << 10) + ((n & 1) << 9) + wroff)) = pk_;   \
    }                                                                         \
  } while (0)

#define G2(G2T, OREG) do {                                                    \
    f32x4 a2_;                                                                \
    a2_[0] = bc2v.x; a2_[1] = bc2v.y; a2_[2] = bc2v.z; a2_[3] = bc2v.w;       \
    const char* pp_ = psm + (((G2T) & 1) << 12);                              \
    _Pragma("unroll")                                                         \
    for (int kk = 0; kk < 4; ++kk) {                                          \
      short8v pb_ = *(const short8v*)(pp_ + ((kk << 10) + rdP));              \
      a2_ = __builtin_amdgcn_mfma_f32_16x16x32_bf16(wcF[kk], pb_, a2_, 0, 0, 0); \
    }                                                                         \
    bool dg_ = (j == i0 + (G2T));                                             \
    OREG.x = dg_ ? 0.f : a2_[0];                                              \
    OREG.y = dg_ ? 0.f : a2_[1];                                              \
    OREG.z = dg_ ? 0.f : a2_[2];                                              \
    OREG.w = dg_ ? 0.f : a2_[3];                                              \
  } while (0)

#define FLUSH(BASE) do {                                                      \
    nt_store4(out + ((size_t)(i0 + (BASE) + 0) * NN + j) * NR + 4 * g, o0);   \
    nt_store4(out + ((size_t)(i0 + (BASE) + 1) * NN + j) * NR + 4 * g, o1);   \
    nt_store4(out + ((size_t)(i0 + (BASE) + 2) * NN + j) * NR + 4 * g, o2);   \
    nt_store4(out + ((size_t)(i0 + (BASE) + 3) * NN + j) * NR + 4 * g, o3);   \
  } while (0)

__global__ __launch_bounds__(256, 1) void k_edge(const float* __restrict__ edge,
                                                 const float* __restrict__ Wc1,
                                                 const float* __restrict__ Wc2,
                                                 const float* __restrict__ bc2,
                                                 const float* __restrict__ Aib,
                                                 const float* __restrict__ Bmat,
                                                 float* __restrict__ out) {
  __shared__ __align__(16) char psm_all[4][2][4096]; // 32 KB P tiles (dbuf per wave)
  __shared__ __align__(16) float aibs[16 * 128];     // 8 KB Aib panel -> 40 KB total
  int tid = threadIdx.x;
  int w = tid >> 6, lane = tid & 63;
  int c = lane & 15, g = lane >> 4;
  int ig = blockIdx.x >> 4, jg = blockIdx.x & 15;
  int i0 = ig * 16;
  int j0w = jg * 64 + w * 16;
  int j = j0w + c;

  // stage Aib panel (16 i x 128 h) into LDS
  {
    int ii = tid >> 4, h8 = (tid & 15) * 8;
    const float4* s = (const float4*)(Aib + (size_t)(i0 + ii) * DD + h8);
    *(float4*)(aibs + ii * 128 + h8)     = s[0];
    *(float4*)(aibs + ii * 128 + h8 + 4) = s[1];
  }

  // We fragments: A1[m=c][k=8g+jj] = Wc1[16n+c][256+8g+jj]
  short8v weF[8];
  #pragma unroll
  for (int n = 0; n < 8; ++n) {
    const float* p = Wc1 + (size_t)(16 * n + c) * 288 + 256 + 8 * g;
    float4 f0 = *(const float4*)p;
    float4 f1 = *(const float4*)(p + 4);
    short8v s;
    s[0]=f2bf(f0.x); s[1]=f2bf(f0.y); s[2]=f2bf(f0.z); s[3]=f2bf(f0.w);
    s[4]=f2bf(f1.x); s[5]=f2bf(f1.y); s[6]=f2bf(f1.z); s[7]=f2bf(f1.w);
    weF[n] = s;
  }
  // Wc2 fragments: A2[m=c][k=32kk+8g+jj]
  short8v wcF[4];
  #pragma unroll
  for (int kk = 0; kk < 4; ++kk) {
    const float* p = Wc2 + (size_t)c * DD + 32 * kk + 8 * g;
    float4 f0 = *(const float4*)p;
    float4 f1 = *(const float4*)(p + 4);
    short8v s;
    s[0]=f2bf(f0.x); s[1]=f2bf(f0.y); s[2]=f2bf(f0.z); s[3]=f2bf(f0.w);
    s[4]=f2bf(f1.x); s[5]=f2bf(f1.y); s[6]=f2bf(f1.z); s[7]=f2bf(f1.w);
    wcF[kk] = s;
  }
  float4 bc2v = *(const float4*)(bc2 + 4 * g);
  // Bmat for this lane's j, reused across all 16 i's
  float4 bjv[8];
  #pragma unroll
  for (int n = 0; n < 8; ++n)
    bjv[n] = *(const float4*)(Bmat + (size_t)j * DD + 16 * n + 4 * g);

  __syncthreads();   // aibs ready

  char* psm = &psm_all[w][0][0];
  // per-lane edge base: lane (c,g) covers (j, dims 8g..8g+7); advance 128KB per i
  const float* ebl = edge + ((size_t)i0 * NN + j) * EDIM + 8 * g;
  // P-tile write/read offsets (derived conflict-free transpose layout)
  int wroff = (c << 4) + ((g & 1) << 3) + ((g >> 1) << 8);
  int rdP   = (g << 8) + (c << 4);

  float4 o0, o1, o2, o3;

  // prologue: fill rotation slots 0..5 with bodies 0..5 (12 loads in flight)
  float4 eA0, eB0, eA1, eB1, eA2, eB2, eA3, eB3, eA4, eB4, eA5, eB5;
  {
    const size_t STP = (size_t)NN * EDIM;
    eA0 = *(const float4*)(ebl);            eB0 = *(const float4*)(ebl + 4);
    eA1 = *(const float4*)(ebl + STP);      eB1 = *(const float4*)(ebl + STP + 4);
    eA2 = *(const float4*)(ebl + 2 * STP);  eB2 = *(const float4*)(ebl + 2 * STP + 4);
    eA3 = *(const float4*)(ebl + 3 * STP);  eB3 = *(const float4*)(ebl + 3 * STP + 4);
    eA4 = *(const float4*)(ebl + 4 * STP);  eB4 = *(const float4*)(ebl + 4 * STP + 4);
    eA5 = *(const float4*)(ebl + 5 * STP);  eB5 = *(const float4*)(ebl + 5 * STP + 4);
  }

  EDGE_BODY(0, 0, 1);
  EDGE_BODY(1, 1, 1);  G2(0, o0);
  EDGE_BODY(2, 2, 1);  G2(1, o1);
  EDGE_BODY(3, 3, 1);  G2(2, o2);
  EDGE_BODY(4, 4, 1);  G2(3, o3);  FLUSH(0);
  EDGE_BODY(5, 5, 1);  G2(4, o0);
  EDGE_BODY(6, 0, 1);  G2(5, o1);
  EDGE_BODY(7, 1, 1);  G2(6, o2);
  EDGE_BODY(8, 2, 1);  G2(7, o3);  FLUSH(4);
  EDGE_BODY(9, 3, 1);  G2(8, o0);
  EDGE_BODY(10, 4, 0); G2(9, o1);
  EDGE_BODY(11, 5, 0); G2(10, o2);
  EDGE_BODY(12, 0, 0); G2(11, o3); FLUSH(8);
  EDGE_BODY(13, 1, 0); G2(12, o0);
  EDGE_BODY(14, 2, 0); G2(13, o1);
  EDGE_BODY(15, 3, 0); G2(14, o2);
  G2(15, o3); FLUSH(12);
}

extern "C" void kernel_launch(void* const* d_in, const int* in_sizes, int n_in,
                              void* d_out, int out_size, void* d_ws, size_t ws_size,
                              hipStream_t stream) {
  const float* node_feat = (const float*)d_in[0];
  const float* edge_feat = (const float*)d_in[1];
  const float* adj  = (const float*)d_in[2];
  const float* W_g1 = (const float*)d_in[3];
  const float* b_g1 = (const float*)d_in[4];
  const float* W_g2 = (const float*)d_in[5];
  const float* b_g2 = (const float*)d_in[6];
  const float* W_c1 = (const float*)d_in[7];
  const float* b_c1 = (const float*)d_in[8];
  const float* W_c2 = (const float*)d_in[9];
  const float* b_c2 = (const float*)d_in[10];
  float* out = (float*)d_out;

  float* ws    = (float*)d_ws;
  float* rsinv = ws;                        // 1024
  float* part  = ws + 1024;                 // 8*1024*128
  float* h1    = part + 8 * NN * DD;        // 131072
  float* Aib   = h1 + NN * DD;              // 131072
  float* Bmat  = Aib + NN * DD;             // 131072

  // layer 1 (rowsum fused into dense1)
  k_adjgemm<<<512, 256, 0, stream>>>(adj, node_feat, part);
  k_dense1<<<512, 256, 0, stream>>>(node_feat, part, adj, W_g1, b_g1, h1, rsinv);
  // layer 2 (+ Aib/Bmat head precompute fused)
  k_adjgemm<<<512, 256, 0, stream>>>(adj, h1, part);
  k_dense2ab<<<512, 256, 0, stream>>>(h1, part, rsinv, W_g2, b_g2, W_c1, b_c1, Aib, Bmat);
  // fused edge stage: 1024 blocks x 4 waves; wave = 16 j x 16 i
  k_edge<<<1024, 256, 0, stream>>>(edge_feat, W_c1, W_c2, b_c2, Aib, Bmat, out);
}

// Round 14
// 122.761 us; speedup vs baseline: 1.0437x; 1.0437x over previous
//
#include <hip/hip_runtime.h>
#include <hip/hip_bf16.h>
#include <stdint.h>

constexpr int NN = 1024;   // nodes
constexpr int DD = 128;    // NODE_DIM == HID
constexpr int EDIM = 32;   // EDGE_DIM
constexpr int NR = 16;     // NREL

using short4v = __attribute__((ext_vector_type(4))) short;
using short8v = __attribute__((ext_vector_type(8))) short;
using f32x4   = __attribute__((ext_vector_type(4))) float;

__device__ __forceinline__ short f2bf(float x) {
  __hip_bfloat16 h = __float2bfloat16(x);   // RNE
  return __builtin_bit_cast(short, h);
}

__device__ __forceinline__ void nt_store4(float* p, const float4& v) {
  f32x4 t;
  t[0] = v.x; t[1] = v.y; t[2] = v.z; t[3] = v.w;
  __builtin_nontemporal_store(t, (f32x4*)p);
}

// ---------------- K_transp: dst[c][r] = bf16(src[r][c]), R=1024, C=128 ----------
__global__ __launch_bounds__(256) void k_transp(const float* __restrict__ src,
                                                short* __restrict__ dst) {
  __shared__ float tile[32][33];
  int b = blockIdx.x;
  int r0 = (b & 31) * 32, c0 = (b >> 5) * 32;
  int t = threadIdx.x;
  {
    int rr = t >> 3, c4 = (t & 7) * 4;
    float4 v = *(const float4*)(src + (size_t)(r0 + rr) * DD + c0 + c4);
    tile[rr][c4]     = v.x;
    tile[rr][c4 + 1] = v.y;
    tile[rr][c4 + 2] = v.z;
    tile[rr][c4 + 3] = v.w;
  }
  __syncthreads();
  {
    int cc = t >> 3, r4 = (t & 7) * 4;
    short4v s;
    s[0] = f2bf(tile[r4 + 0][cc]);
    s[1] = f2bf(tile[r4 + 1][cc]);
    s[2] = f2bf(tile[r4 + 2][cc]);
    s[3] = f2bf(tile[r4 + 3][cc]);
    *(short4v*)(dst + (size_t)(c0 + cc) * NN + r0 + r4) = s;
  }
}

// ---------------- K_adjmm: part[kc][i][h] = sum_{k in kc} adj[i][k]*X[k][h] -------
// MFMA 16x16x32 bf16. A = XT[h][k] (bf16, contiguous frags), B = adj^T (f32->bf16
// in-reg; adj[i][k] row-major IS B[k][col=i] fragment layout). No LDS.
// grid 256: b = kc*64 + hc*16 + ic; wave w: i0 = ic*64 + w*16. K=256 per block.
__global__ __launch_bounds__(256) void k_adjmm(const short* __restrict__ XT,
                                               const float* __restrict__ adj,
                                               float* __restrict__ part) {
  int t = threadIdx.x;
  int w = t >> 6, lane = t & 63;
  int c = lane & 15, g = lane >> 4;
  int b = blockIdx.x;
  int ic = b & 15, hc = (b >> 4) & 3, kc = b >> 6;
  int i0 = ic * 64 + w * 16, h0 = hc * 32;
  size_t kb = (size_t)kc * 256 + 8 * g;

  f32x4 acc0 = {0, 0, 0, 0}, acc1 = {0, 0, 0, 0};
  const short* xa0 = XT + (size_t)(h0 + c) * NN + kb;
  const short* xa1 = XT + (size_t)(h0 + 16 + c) * NN + kb;
  const float* ba  = adj + (size_t)(i0 + c) * NN + kb;
  #pragma unroll
  for (int ks = 0; ks < 8; ++ks) {
    short8v a0 = *(const short8v*)(xa0 + ks * 32);
    short8v a1 = *(const short8v*)(xa1 + ks * 32);
    float4 b0 = *(const float4*)(ba + ks * 32);
    float4 b1 = *(const float4*)(ba + ks * 32 + 4);
    short8v bb;
    bb[0] = f2bf(b0.x); bb[1] = f2bf(b0.y); bb[2] = f2bf(b0.z); bb[3] = f2bf(b0.w);
    bb[4] = f2bf(b1.x); bb[5] = f2bf(b1.y); bb[6] = f2bf(b1.z); bb[7] = f2bf(b1.w);
    acc0 = __builtin_amdgcn_mfma_f32_16x16x32_bf16(a0, bb, acc0, 0, 0, 0);
    acc1 = __builtin_amdgcn_mfma_f32_16x16x32_bf16(a1, bb, acc1, 0, 0, 0);
  }
  // D layout: col=c -> i, row=4g+r -> h (within 16-tile) -> float4 store
  float* p0 = part + ((size_t)kc * NN + (i0 + c)) * DD + h0 + 4 * g;
  float4 o0 = {acc0[0], acc0[1], acc0[2], acc0[3]};
  float4 o1 = {acc1[0], acc1[1], acc1[2], acc1[3]};
  *(float4*)(p0)      = o0;
  *(float4*)(p0 + 16) = o1;
}

// ---------------- K_dense1: rowsum + aggfin + dense layer1 ----------------
__global__ __launch_bounds__(256) void k_dense1(const float* __restrict__ X,
                                                const float* __restrict__ part,
                                                const float* __restrict__ adj,
                                                const float* __restrict__ W,
                                                const float* __restrict__ b,
                                                float* __restrict__ out,
                                                float* __restrict__ rsinv) {
  __shared__ float sagg[2][128];
  __shared__ float red[4];
  int t = threadIdx.x;
  int ig = t >> 7, h = t & 127;
  int i = blockIdx.x * 2 + ig;
  {   // rowsum(adj[i]) : 128 threads x 8 floats (adj L2-hot)
    const float4* ar = (const float4*)(adj + (size_t)i * NN);
    float4 v0 = ar[h * 2], v1 = ar[h * 2 + 1];
    float s = v0.x + v0.y + v0.z + v0.w + v1.x + v1.y + v1.z + v1.w;
    #pragma unroll
    for (int off = 32; off > 0; off >>= 1) s += __shfl_down(s, off, 64);
    if ((t & 63) == 0) red[t >> 6] = s;
  }
  __syncthreads();
  float rs = 1.0f / (red[ig * 2] + red[ig * 2 + 1] + 1e-6f);
  if (h == 0) rsinv[i] = rs;
  {
    float ss = 0.f;
    #pragma unroll
    for (int kc = 0; kc < 4; ++kc) ss += part[(size_t)kc * NN * DD + (size_t)i * DD + h];
    sagg[ig][h] = ss * rs;
  }
  __syncthreads();
  const float4* xr = (const float4*)(X + (size_t)i * DD);
  const float4* ar = (const float4*)(&sagg[ig][0]);
  const float4* w1 = (const float4*)(W + (size_t)h * 256);
  const float4* w2 = (const float4*)(W + (size_t)h * 256 + DD);
  float acc = b[h];
  #pragma unroll 8
  for (int k = 0; k < 32; ++k) {
    float4 x = xr[k], w = w1[k];
    acc += x.x * w.x + x.y * w.y + x.z * w.z + x.w * w.w;
  }
  #pragma unroll 8
  for (int k = 0; k < 32; ++k) {
    float4 y = ar[k], w = w2[k];
    acc += y.x * w.x + y.y * w.y + y.z * w.z + y.w * w.w;
  }
  out[(size_t)i * DD + h] = fmaxf(acc, 0.f);
}

// ---------------- K_dense2ab: aggfin + dense layer2 + Aib/Bmat, fused ------------
__global__ __launch_bounds__(256) void k_dense2ab(const float* __restrict__ X,
                                                  const float* __restrict__ part,
                                                  const float* __restrict__ rsinv,
                                                  const float* __restrict__ W,
                                                  const float* __restrict__ b,
                                                  const float* __restrict__ Wc1,
                                                  const float* __restrict__ bc1,
                                                  float* __restrict__ Aib,
                                                  float* __restrict__ Bmat) {
  __shared__ float sagg[2][128];
  __shared__ float sh2[2][128];
  int t = threadIdx.x;
  int ig = t >> 7, h = t & 127;
  int i = blockIdx.x * 2 + ig;
  {
    float ss = 0.f;
    #pragma unroll
    for (int kc = 0; kc < 4; ++kc) ss += part[(size_t)kc * NN * DD + (size_t)i * DD + h];
    sagg[ig][h] = ss * rsinv[i];
  }
  __syncthreads();
  {
    const float4* xr = (const float4*)(X + (size_t)i * DD);
    const float4* ar = (const float4*)(&sagg[ig][0]);
    const float4* w1 = (const float4*)(W + (size_t)h * 256);
    const float4* w2 = (const float4*)(W + (size_t)h * 256 + DD);
    float acc = b[h];
    #pragma unroll 8
    for (int k = 0; k < 32; ++k) {
      float4 x = xr[k], w = w1[k];
      acc += x.x * w.x + x.y * w.y + x.z * w.z + x.w * w.w;
    }
    #pragma unroll 8
    for (int k = 0; k < 32; ++k) {
      float4 y = ar[k], w = w2[k];
      acc += y.x * w.x + y.y * w.y + y.z * w.z + y.w * w.w;
    }
    sh2[ig][h] = fmaxf(acc, 0.f);
  }
  __syncthreads();
  const float4* xr = (const float4*)(&sh2[ig][0]);
  const float4* wa = (const float4*)(Wc1 + (size_t)h * 288);
  const float4* wb = (const float4*)(Wc1 + (size_t)h * 288 + 128);
  float aa = bc1[h], bb = 0.f;
  #pragma unroll 8
  for (int k = 0; k < 32; ++k) {
    float4 x = xr[k];
    float4 a = wa[k], b2 = wb[k];
    aa += x.x * a.x + x.y * a.y + x.z * a.z + x.w * a.w;
    bb += x.x * b2.x + x.y * b2.y + x.z * b2.z + x.w * b2.w;
  }
  Aib[(size_t)i * DD + h] = aa;
  Bmat[(size_t)i * DD + h] = bb;
}

// ---------------- K7: fused edge stage (unchanged from R13) ----------------
#define EDGE_BODY(T, S, PF) do {                                              \
    float4 a_ = eA##S, b_ = eB##S;                                            \
    if (PF) {                                                                 \
      const float* p_ = ebl + (size_t)((T) + 6) * ((size_t)NN * EDIM);        \
      eA##S = *(const float4*)p_;                                             \
      eB##S = *(const float4*)(p_ + 4);                                       \
    }                                                                         \
    short8v ef_;                                                              \
    ef_[0]=f2bf(a_.x); ef_[1]=f2bf(a_.y); ef_[2]=f2bf(a_.z); ef_[3]=f2bf(a_.w); \
    ef_[4]=f2bf(b_.x); ef_[5]=f2bf(b_.y); ef_[6]=f2bf(b_.z); ef_[7]=f2bf(b_.w); \
    char* pw_ = psm + (((T) & 1) << 12);                                      \
    const float* ap_ = aibs + (T) * 128 + 4 * g;                              \
    _Pragma("unroll")                                                         \
    for (int n = 0; n < 8; ++n) {                                             \
      float4 av_ = *(const float4*)(ap_ + 16 * n);                            \
      f32x4 ci_;                                                              \
      ci_[0] = av_.x + bjv[n].x; ci_[1] = av_.y + bjv[n].y;                   \
      ci_[2] = av_.z + bjv[n].z; ci_[3] = av_.w + bjv[n].w;                   \
      f32x4 acc_ = __builtin_amdgcn_mfma_f32_16x16x32_bf16(weF[n], ef_, ci_, 0, 0, 0); \
      short4v pk_;                                                            \
      pk_[0] = f2bf(fmaxf(acc_[0], 0.f)); pk_[1] = f2bf(fmaxf(acc_[1], 0.f)); \
      pk_[2] = f2bf(fmaxf(acc_[2], 0.f)); pk_[3] = f2bf(fmaxf(acc_[3], 0.f)); \
      *(short4v*)(pw_ + (((n >> 1) << 10) + ((n & 1) << 9) + wroff)) = pk_;   \
    }                                                                         \
  } while (0)

#define G2(G2T, OREG) do {                                                    \
    f32x4 a2_;                                                                \
    a2_[0] = bc2v.x; a2_[1] = bc2v.y; a2_[2] = bc2v.z; a2_[3] = bc2v.w;       \
    const char* pp_ = psm + (((G2T) & 1) << 12);                              \
    _Pragma("unroll")                                                         \
    for (int kk = 0; kk < 4; ++kk) {                                          \
      short8v pb_ = *(const short8v*)(pp_ + ((kk << 10) + rdP));              \
      a2_ = __builtin_amdgcn_mfma_f32_16x16x32_bf16(wcF[kk], pb_, a2_, 0, 0, 0); \
    }                                                                         \
    bool dg_ = (j == i0 + (G2T));                                             \
    OREG.x = dg_ ? 0.f : a2_[0];                                              \
    OREG.y = dg_ ? 0.f : a2_[1];                                              \
    OREG.z = dg_ ? 0.f : a2_[2];                                              \
    OREG.w = dg_ ? 0.f : a2_[3];                                              \
  } while (0)

#define FLUSH(BASE) do {                                                      \
    nt_store4(out + ((size_t)(i0 + (BASE) + 0) * NN + j) * NR + 4 * g, o0);   \
    nt_store4(out + ((size_t)(i0 + (BASE) + 1) * NN + j) * NR + 4 * g, o1);   \
    nt_store4(out + ((size_t)(i0 + (BASE) + 2) * NN + j) * NR + 4 * g, o2);   \
    nt_store4(out + ((size_t)(i0 + (BASE) + 3) * NN + j) * NR + 4 * g, o3);   \
  } while (0)

__global__ __launch_bounds__(256, 1) void k_edge(const float* __restrict__ edge,
                                                 const float* __restrict__ Wc1,
                                                 const float* __restrict__ Wc2,
                                                 const float* __restrict__ bc2,
                                                 const float* __restrict__ Aib,
                                                 const float* __restrict__ Bmat,
                                                 float* __restrict__ out) {
  __shared__ __align__(16) char psm_all[4][2][4096]; // 32 KB P tiles (dbuf per wave)
  __shared__ __align__(16) float aibs[16 * 128];     // 8 KB Aib panel -> 40 KB total
  int tid = threadIdx.x;
  int w = tid >> 6, lane = tid & 63;
  int c = lane & 15, g = lane >> 4;
  int ig = blockIdx.x >> 4, jg = blockIdx.x & 15;
  int i0 = ig * 16;
  int j0w = jg * 64 + w * 16;
  int j = j0w + c;

  {
    int ii = tid >> 4, h8 = (tid & 15) * 8;
    const float4* s = (const float4*)(Aib + (size_t)(i0 + ii) * DD + h8);
    *(float4*)(aibs + ii * 128 + h8)     = s[0];
    *(float4*)(aibs + ii * 128 + h8 + 4) = s[1];
  }

  short8v weF[8];
  #pragma unroll
  for (int n = 0; n < 8; ++n) {
    const float* p = Wc1 + (size_t)(16 * n + c) * 288 + 256 + 8 * g;
    float4 f0 = *(const float4*)p;
    float4 f1 = *(const float4*)(p + 4);
    short8v s;
    s[0]=f2bf(f0.x); s[1]=f2bf(f0.y); s[2]=f2bf(f0.z); s[3]=f2bf(f0.w);
    s[4]=f2bf(f1.x); s[5]=f2bf(f1.y); s[6]=f2bf(f1.z); s[7]=f2bf(f1.w);
    weF[n] = s;
  }
  short8v wcF[4];
  #pragma unroll
  for (int kk = 0; kk < 4; ++kk) {
    const float* p = Wc2 + (size_t)c * DD + 32 * kk + 8 * g;
    float4 f0 = *(const float4*)p;
    float4 f1 = *(const float4*)(p + 4);
    short8v s;
    s[0]=f2bf(f0.x); s[1]=f2bf(f0.y); s[2]=f2bf(f0.z); s[3]=f2bf(f0.w);
    s[4]=f2bf(f1.x); s[5]=f2bf(f1.y); s[6]=f2bf(f1.z); s[7]=f2bf(f1.w);
    wcF[kk] = s;
  }
  float4 bc2v = *(const float4*)(bc2 + 4 * g);
  float4 bjv[8];
  #pragma unroll
  for (int n = 0; n < 8; ++n)
    bjv[n] = *(const float4*)(Bmat + (size_t)j * DD + 16 * n + 4 * g);

  __syncthreads();   // aibs ready

  char* psm = &psm_all[w][0][0];
  const float* ebl = edge + ((size_t)i0 * NN + j) * EDIM + 8 * g;
  int wroff = (c << 4) + ((g & 1) << 3) + ((g >> 1) << 8);
  int rdP   = (g << 8) + (c << 4);

  float4 o0, o1, o2, o3;

  float4 eA0, eB0, eA1, eB1, eA2, eB2, eA3, eB3, eA4, eB4, eA5, eB5;
  {
    const size_t STP = (size_t)NN * EDIM;
    eA0 = *(const float4*)(ebl);            eB0 = *(const float4*)(ebl + 4);
    eA1 = *(const float4*)(ebl + STP);      eB1 = *(const float4*)(ebl + STP + 4);
    eA2 = *(const float4*)(ebl + 2 * STP);  eB2 = *(const float4*)(ebl + 2 * STP + 4);
    eA3 = *(const float4*)(ebl + 3 * STP);  eB3 = *(const float4*)(ebl + 3 * STP + 4);
    eA4 = *(const float4*)(ebl + 4 * STP);  eB4 = *(const float4*)(ebl + 4 * STP + 4);
    eA5 = *(const float4*)(ebl + 5 * STP);  eB5 = *(const float4*)(ebl + 5 * STP + 4);
  }

  EDGE_BODY(0, 0, 1);
  EDGE_BODY(1, 1, 1);  G2(0, o0);
  EDGE_BODY(2, 2, 1);  G2(1, o1);
  EDGE_BODY(3, 3, 1);  G2(2, o2);
  EDGE_BODY(4, 4, 1);  G2(3, o3);  FLUSH(0);
  EDGE_BODY(5, 5, 1);  G2(4, o0);
  EDGE_BODY(6, 0, 1);  G2(5, o1);
  EDGE_BODY(7, 1, 1);  G2(6, o2);
  EDGE_BODY(8, 2, 1);  G2(7, o3);  FLUSH(4);
  EDGE_BODY(9, 3, 1);  G2(8, o0);
  EDGE_BODY(10, 4, 0); G2(9, o1);
  EDGE_BODY(11, 5, 0); G2(10, o2);
  EDGE_BODY(12, 0, 0); G2(11, o3); FLUSH(8);
  EDGE_BODY(13, 1, 0); G2(12, o0);
  EDGE_BODY(14, 2, 0); G2(13, o1);
  EDGE_BODY(15, 3, 0); G2(14, o2);
  G2(15, o3); FLUSH(12);
}

extern "C" void kernel_launch(void* const* d_in, const int* in_sizes, int n_in,
                              void* d_out, int out_size, void* d_ws, size_t ws_size,
                              hipStream_t stream) {
  const float* node_feat = (const float*)d_in[0];
  const float* edge_feat = (const float*)d_in[1];
  const float* adj  = (const float*)d_in[2];
  const float* W_g1 = (const float*)d_in[3];
  const float* b_g1 = (const float*)d_in[4];
  const float* W_g2 = (const float*)d_in[5];
  const float* b_g2 = (const float*)d_in[6];
  const float* W_c1 = (const float*)d_in[7];
  const float* b_c1 = (const float*)d_in[8];
  const float* W_c2 = (const float*)d_in[9];
  const float* b_c2 = (const float*)d_in[10];
  float* out = (float*)d_out;

  float* ws    = (float*)d_ws;
  float* rsinv = ws;                        // 1024
  float* part  = ws + 1024;                 // 4*1024*128 = 524288
  float* h1    = part + 4 * NN * DD;        // 131072
  float* Aib   = h1 + NN * DD;              // 131072
  float* Bmat  = Aib + NN * DD;             // 131072
  short* XT1   = (short*)(Bmat + NN * DD);  // 128*1024 shorts
  short* XT2   = XT1 + DD * NN;             // 128*1024 shorts

  // layer 1: transpose node_feat -> MFMA adj@X -> dense (rowsum fused)
  k_transp<<<128, 256, 0, stream>>>(node_feat, XT1);
  k_adjmm<<<256, 256, 0, stream>>>(XT1, adj, part);
  k_dense1<<<512, 256, 0, stream>>>(node_feat, part, adj, W_g1, b_g1, h1, rsinv);
  // layer 2: transpose h1 -> MFMA adj@h1 -> dense + Aib/Bmat
  k_transp<<<128, 256, 0, stream>>>(h1, XT2);
  k_adjmm<<<256, 256, 0, stream>>>(XT2, adj, part);
  k_dense2ab<<<512, 256, 0, stream>>>(h1, part, rsinv, W_g2, b_g2, W_c1, b_c1, Aib, Bmat);
  // fused edge stage
  k_edge<<<1024, 256, 0, stream>>>(edge_feat, W_c1, W_c2, b_c2, Aib, Bmat, out);
}